// Round 5
// baseline (174.658 us; speedup 1.0000x reference)
//
#include <hip/hip_runtime.h>
#include <stdint.h>

// Problem constants
#define NROWS 8192
#define DIN   512
#define HIDN  1024
#define EMBN  64
#define NCONS 62      // EMB - N_EFF
#define NCLS  16
#define MARGINF 0.01f
#define NREP  16      // vsum replication factor (atomic contention /16)

typedef unsigned short u16;
typedef __attribute__((ext_vector_type(8))) short short8;   // 8 bf16 (4 VGPRs)
typedef __attribute__((ext_vector_type(4))) float floatx4;  // 4 fp32 acc

__device__ __forceinline__ u16 f32_to_bf16(float f) {
  union { float f; uint32_t u; } x; x.f = f;
  uint32_t u = x.u;
  uint32_t r = (u + 0x7FFFu + ((u >> 16) & 1u)) >> 16;  // RNE
  return (u16)r;
}

__device__ __forceinline__ float bf16_to_f32(u16 h) {
  union { uint32_t u; float f; } x; x.u = (uint32_t)h << 16;
  return x.f;
}

__device__ __forceinline__ float fast_tanh(float x) {
  float xc = fminf(fmaxf(x, -10.f), 10.f);     // clamp: avoid inf/inf
  float e = __expf(2.f * xc);
  return (e - 1.f) * __builtin_amdgcn_rcpf(e + 1.f);
}

__device__ __forceinline__ void load_lds16(const u16* g, u16* l) {
  __builtin_amdgcn_global_load_lds(
      (const __attribute__((address_space(1))) void*)g,
      (__attribute__((address_space(3))) void*)l, 16, 0, 0);
}

// ---------------------------------------------------------------------------
// Weight pre-pack: W (K x N fp32) -> 1KB tiles [nt][ku], tile = 16 n-rows x
// 32 k. Row r's k-chunk c (8 bf16 = 16B) stored at slot c ^ ((r>>1)&3).
// Direct-global frag read: lane for (row=l15, chunk=q) is l15*4 + (q^((l15>>1)&3)).
// ---------------------------------------------------------------------------
__device__ __forceinline__ void pack_tile(const float* __restrict__ W,
                                          u16* __restrict__ Wp,
                                          int N, int KU, int t, int lane)
{
  const int r = lane >> 2, slot = lane & 3;
  const int c = slot ^ ((r >> 1) & 3);
  const int nt = t / KU, ku = t - nt * KU;
  const int n = nt * 16 + r;
  const int kb = ku * 32 + c * 8;
  short8 v;
#pragma unroll
  for (int j = 0; j < 8; ++j) v[j] = (short)f32_to_bf16(W[(size_t)(kb + j) * N + n]);
  *(short8*)(Wp + ((size_t)t * 64 + lane) * 8) = v;
}

// ---------------------------------------------------------------------------
// One kernel for ALL independent prep:
//   blocks [0,2048): x -> A0p (MFMA-A packed bf16); b<32 also labels + a
//   per-block label histogram (plain stores to hist32[32][16]).
//   [2048,2304): pack W1   [2304,2336): pack W2
//   [2336,2368): pack W3   [2368,2624): pack W4
//   [2624,2630): zero 96KB slab (counts/psum/SsumR/vsumR)
// ---------------------------------------------------------------------------
__global__ __launch_bounds__(256)
void prep_all(const float* __restrict__ x,
              const float* __restrict__ W1, const float* __restrict__ W2,
              const float* __restrict__ W3, const float* __restrict__ W4,
              u16* __restrict__ A0p, u16* __restrict__ W1p,
              u16* __restrict__ W2p, u16* __restrict__ W3p,
              u16* __restrict__ W4p, float* __restrict__ slab,
              int* __restrict__ labels, int* __restrict__ hist32)
{
  __shared__ int hh[NCLS];
  const int b = blockIdx.x;
  const int tid = threadIdx.x;
  const int tl = tid >> 6, lane = tid & 63;
  if (b < 2048) {
    if (b < 32) {
      if (tid < NCLS) hh[tid] = 0;
      const int row = b * 256 + tid;
      const int lab = (int)x[(size_t)row * 513];
      labels[row] = lab;
      __syncthreads();
      atomicAdd(&hh[lab], 1);
      __syncthreads();
      if (tid < NCLS) hist32[b * NCLS + tid] = hh[tid];
    }
    const int t = b * 4 + tl;
    const int rt = t >> 4, ku = t & 15;
    const int r = lane & 15, q = lane >> 4;
    const float* src = x + (size_t)(rt * 16 + r) * 513 + 1 + ku * 32 + q * 8;
    short8 v;
#pragma unroll
    for (int j = 0; j < 8; ++j) v[j] = (short)f32_to_bf16(src[j]);
    *(short8*)(A0p + ((size_t)t * 64 + lane) * 8) = v;
  } else if (b < 2304) {
    pack_tile(W1, W1p, 1024, 16, (b - 2048) * 4 + tl, lane);
  } else if (b < 2336) {
    pack_tile(W2, W2p, 64, 32, (b - 2304) * 4 + tl, lane);
  } else if (b < 2368) {
    pack_tile(W3, W3p, 1024, 2, (b - 2336) * 4 + tl, lane);
  } else if (b < 2624) {
    pack_tile(W4, W4p, 512, 32, (b - 2368) * 4 + tl, lane);
  } else {
    float* dst = slab + (size_t)(b - 2624) * 4096;
    for (int i = tid; i < 4096; i += 256) dst[i] = 0.f;
  }
}

// ---------------------------------------------------------------------------
// FUSED layers 1+2+3 + stats (round-5). Grid 272 x 512 threads:
//   blocks [0,16): GROUP-SCATTER role (deterministic bases from hist32).
//   blocks [16,272): 32 rows each. 8 waves; wave w owns a PRIVATE 128-col
//     slice -> no inter-wave B sharing -> B read DIRECT from global (L2-hit,
//     W1p 1MB resident/XCD), ZERO barriers in the layer1 K-loop (gemm3
//     pattern). H (32x1024) kept in LDS; layer2 K-split across waves with
//     LDS partial reduce; stats from LDS E; layer3 from LDS E.
// Eliminates: stats3 dispatch, Ef4 fp32 16MB round-trip, 17 barrier-drains,
// 4x redundant A reads. 4 barriers total.
// ---------------------------------------------------------------------------
__global__ __launch_bounds__(512)
void fused123(const u16* __restrict__ A0p, const u16* __restrict__ W1p,
              const float* __restrict__ b1, const u16* __restrict__ W2p,
              const float* __restrict__ b2, const u16* __restrict__ W3p,
              const float* __restrict__ b3,
              const int* __restrict__ labels, const int* __restrict__ hist32,
              int* __restrict__ offs, int* __restrict__ counts,
              int* __restrict__ idx,
              u16* __restrict__ Ebf, float* __restrict__ sqrow,
              float* __restrict__ vsumR, float* __restrict__ SsumR,
              u16* __restrict__ T)
{
  __shared__ u16 uni[33024];        // 66KB: Hc[32][1032] bf16 / Epart[8][32][64] f32
  __shared__ u16 El[32 * 66];       // 4.2 KB
  __shared__ float lv[NCLS][64];    // 4 KB
  __shared__ float lsq[NCLS][64];   // 4 KB
  __shared__ int colsum[NCLS], preblk[NCLS], scur[NCLS];

  const int tid = threadIdx.x;

  if (blockIdx.x < 16) {
    // ---- scatter role ----
    const int sb = blockIdx.x;      // 0..15
    if (tid < NCLS) {
      int s = 0, p = 0;
      for (int b2i = 0; b2i < 32; ++b2i) {
        const int h = hist32[b2i * NCLS + tid];
        s += h;
        if (b2i < sb * 2) p += h;
      }
      colsum[tid] = s;
      preblk[tid] = p;
    }
    __syncthreads();
    if (tid < NCLS) {
      int o = 0;
      for (int c = 0; c < tid; ++c) o += colsum[c];
      scur[tid] = o + preblk[tid];
      if (sb == 0) {
        counts[tid] = colsum[tid];
        offs[tid] = o;
        if (tid == NCLS - 1) offs[NCLS] = o + colsum[NCLS - 1];
      }
    }
    __syncthreads();
    {
      const int row = sb * 512 + tid;
      const int p = atomicAdd(&scur[labels[row]], 1);
      idx[p] = row;
    }
    return;
  }

  // ---- compute role ----
  const int bx = blockIdx.x - 16;   // 0..255
  const int m0 = bx * 32;
  const int rep = blockIdx.x & (NREP - 1);
  const int w = tid >> 6, lane = tid & 63;
  const int quad = lane >> 4, l15 = lane & 15;
  const int lamb = l15 * 4 + (quad ^ ((l15 >> 1) & 3));  // pack-permuted lane

  for (int i = tid; i < NCLS * 64; i += 512) {
    ((float*)lv)[i] = 0.f; ((float*)lsq)[i] = 0.f;
  }

  u16* Hc = uni;                    // [32][1032] bf16
  float* Epart = (float*)uni;       // [8][32][64] f32 (overlay, after barrier 2)

  // ======== layer1: H = tanh(A @ W1 + b1), wave w -> cols [w*128,(w+1)*128)
  floatx4 acc1[2][8];
#pragma unroll
  for (int i = 0; i < 2; ++i)
#pragma unroll
    for (int jj = 0; jj < 8; ++jj) acc1[i][jj] = (floatx4){0.f, 0.f, 0.f, 0.f};

  for (int s = 0; s < 16; ++s) {
    short8 af[2];
#pragma unroll
    for (int i = 0; i < 2; ++i)
      af[i] = *(const short8*)(A0p + (size_t)((bx * 2 + i) * 16 + s) * 512 + lane * 8);
#pragma unroll
    for (int jj = 0; jj < 8; ++jj) {
      const short8 bf = *(const short8*)(W1p + (size_t)((w * 8 + jj) * 16 + s) * 512 + lamb * 8);
#pragma unroll
      for (int i = 0; i < 2; ++i)
        acc1[i][jj] = __builtin_amdgcn_mfma_f32_16x16x32_bf16(af[i], bf, acc1[i][jj], 0, 0, 0);
    }
  }
#pragma unroll
  for (int jj = 0; jj < 8; ++jj) {
    const int col = w * 128 + jj * 16 + l15;
    const float bv = b1[col];
#pragma unroll
    for (int i = 0; i < 2; ++i)
#pragma unroll
      for (int r = 0; r < 4; ++r)
        Hc[(i * 16 + quad * 4 + r) * 1032 + col] = f32_to_bf16(fast_tanh(acc1[i][jj][r] + bv));
  }
  __syncthreads();   // (1) Hc complete

  // ======== layer2: E = H @ W2 (32x64), K-split: wave w sums H cols [w*128,+128)
  floatx4 acc2[2][4];
#pragma unroll
  for (int i = 0; i < 2; ++i)
#pragma unroll
    for (int nt = 0; nt < 4; ++nt) acc2[i][nt] = (floatx4){0.f, 0.f, 0.f, 0.f};

#pragma unroll
  for (int kk = 0; kk < 4; ++kk) {
    const int ku = w * 4 + kk;
    short8 af[2];
#pragma unroll
    for (int i = 0; i < 2; ++i)
      af[i] = *(const short8*)(Hc + (i * 16 + l15) * 1032 + ku * 32 + quad * 8);
#pragma unroll
    for (int nt = 0; nt < 4; ++nt) {
      const short8 bf = *(const short8*)(W2p + (size_t)(nt * 32 + ku) * 512 + lamb * 8);
#pragma unroll
      for (int i = 0; i < 2; ++i)
        acc2[i][nt] = __builtin_amdgcn_mfma_f32_16x16x32_bf16(af[i], bf, acc2[i][nt], 0, 0, 0);
    }
  }
  __syncthreads();   // (2) all Hc reads done -> overlay safe

#pragma unroll
  for (int i = 0; i < 2; ++i)
#pragma unroll
    for (int nt = 0; nt < 4; ++nt)
#pragma unroll
      for (int r = 0; r < 4; ++r)
        Epart[((size_t)w * 32 + i * 16 + quad * 4 + r) * 64 + nt * 16 + l15] = acc2[i][nt][r];
  __syncthreads();   // (3) partials complete

  // ======== reduce 8 partials + b2 -> Ebf/El + stats (waves 0..3, 8 rows each)
  if (w < 4) {
    const float bv2 = b2[lane];
    for (int r = 0; r < 8; ++r) {
      const int row = w * 8 + r;
      const int grow = m0 + row;
      const int c = labels[grow];
      float acc = bv2;
#pragma unroll
      for (int p = 0; p < 8; ++p)
        acc += Epart[((size_t)p * 32 + row) * 64 + lane];
      const u16 h = f32_to_bf16(acc);
      Ebf[(size_t)grow * 64 + lane] = h;
      El[row * 66 + lane] = h;
      float v = bf16_to_f32(h);
      if (lane < 2) v = 0.f;
      const float v2 = v * v;
      atomicAdd(&lv[c][lane], v);
      atomicAdd(&lsq[c][lane], v2);
      float s = v2;
      for (int o = 32; o > 0; o >>= 1) s += __shfl_xor(s, o);
      if (lane == 0) sqrow[grow] = s;
    }
  }
  __syncthreads();   // (4) El + lv/lsq complete

  // flush per-class sums to replicated global accumulators
  for (int i = tid; i < NCLS * 64; i += 512) {
    const int c = i >> 6, k = i & 63;
    if (k >= 2) atomicAdd(&vsumR[rep * (NCLS * NCONS) + c * NCONS + k - 2], lv[c][k]);
  }
  if (tid < NCLS) {
    float s = 0.f;
    for (int k = 0; k < 64; ++k) s += lsq[tid][k];
    atomicAdd(&SsumR[rep * NCLS + tid], s);
  }

  // ======== layer3: T = tanh(E @ W3 + b3), wave w -> cols [w*128,(w+1)*128)
  floatx4 acc3[2][8];
#pragma unroll
  for (int i = 0; i < 2; ++i)
#pragma unroll
    for (int jj = 0; jj < 8; ++jj) acc3[i][jj] = (floatx4){0.f, 0.f, 0.f, 0.f};

#pragma unroll
  for (int kk = 0; kk < 2; ++kk) {
    short8 af[2];
#pragma unroll
    for (int i = 0; i < 2; ++i)
      af[i] = *(const short8*)(El + (i * 16 + l15) * 66 + kk * 32 + quad * 8);
#pragma unroll
    for (int jj = 0; jj < 8; ++jj) {
      const int nt = w * 8 + jj;
      const short8 bf = *(const short8*)(W3p + (size_t)(nt * 2 + kk) * 512 + lamb * 8);
#pragma unroll
      for (int i = 0; i < 2; ++i)
        acc3[i][jj] = __builtin_amdgcn_mfma_f32_16x16x32_bf16(af[i], bf, acc3[i][jj], 0, 0, 0);
    }
  }
#pragma unroll
  for (int jj = 0; jj < 8; ++jj) {
    const int col = w * 128 + jj * 16 + l15;
    const float bv3 = b3[col];
#pragma unroll
    for (int i = 0; i < 2; ++i)
#pragma unroll
      for (int r = 0; r < 4; ++r)
        T[(size_t)(m0 + i * 16 + quad * 4 + r) * 1024 + col] =
            f32_to_bf16(fast_tanh(acc3[i][jj][r] + bv3));
  }
}

// ---------------------------------------------------------------------------
// MERGED tail: blocks [0,512) = layer4 GEMM (out = T @ W4 + b4, 128x64 tile,
// XCD-aware remap), blocks [512,848) = same-class pairwise hinge (128x128
// pair-tiles). Union LDS 48 KB.
// ---------------------------------------------------------------------------
__global__ __launch_bounds__(256)
void tail(const u16* __restrict__ T, const u16* __restrict__ W4p,
          const float* __restrict__ b4, float* __restrict__ out,
          const u16* __restrict__ Ebf, const float* __restrict__ sqrow,
          const int* __restrict__ idx, const int* __restrict__ offs,
          float* __restrict__ pair_sum)
{
  __shared__ u16 uni[24576];        // 48 KB union
  const int tid = threadIdx.x, wave = tid >> 6, lane = tid & 63;
  const int quad = lane >> 4, l15 = lane & 15;

  if (blockIdx.x < 512) {
    // ================= gemm4 role =================
    u16* lA = uni;                  // [2][16*512] = 32 KB
    u16* lBb = uni + 16384;         // [2][8*512]  = 16 KB
    const int wm = wave >> 1, wn = wave & 1;
    const int xslot = (l15 >> 1) & 3;
    const int lin = blockIdx.x;     // 0..511
    const int n0 = (lin >> 6) * 64;    // 8 n-tiles
    const int m0 = (lin & 63) * 128;   // 64 m-panels; same panel -> same lin%8
    const int srow = lane >> 2;                        // row within 16-row unit
    const int schunk = (lane & 3) ^ ((lane >> 3) & 3); // XOR chunk swizzle

    auto stage = [&](int s, int buf) {
#pragma unroll
      for (int q = 0; q < 6; ++q) {
        const int u = wave + q * 4;
        if (u < 16) {
          const int rg = u >> 1, kh = u & 1;
          load_lds16(T + (size_t)(m0 + rg * 16 + srow) * 1024 + s * 64 + kh * 32 + schunk * 8,
                     lA + buf * 8192 + u * 512 + lane * 8);
        } else {
          const int v = u - 16, nt = v >> 1, kh = v & 1;
          load_lds16(W4p + (size_t)(((n0 >> 4) + nt) * 32 + s * 2 + kh) * 512 + lane * 8,
                     lBb + buf * 4096 + v * 512 + lane * 8);
        }
      }
    };

    stage(0, 0);
    __syncthreads();

    floatx4 acc[4][2];
#pragma unroll
    for (int i = 0; i < 4; ++i)
#pragma unroll
      for (int j = 0; j < 2; ++j) acc[i][j] = (floatx4){0.f, 0.f, 0.f, 0.f};

    for (int s = 0; s < 16; ++s) {
      const int p = s & 1;
      if (s < 15) stage(s + 1, 1 - p);
#pragma unroll
      for (int kk = 0; kk < 2; ++kk) {
        short8 af[4], bf[2];
#pragma unroll
        for (int i = 0; i < 4; ++i)
          af[i] = *(const short8*)(lA + p * 8192 + ((wm * 4 + i) * 2 + kk) * 512
                                   + l15 * 32 + ((quad ^ xslot) << 3));
#pragma unroll
        for (int j = 0; j < 2; ++j)
          bf[j] = *(const short8*)(lBb + p * 4096 + ((wn * 2 + j) * 2 + kk) * 512
                                   + l15 * 32 + ((quad ^ xslot) << 3));
#pragma unroll
        for (int i = 0; i < 4; ++i)
#pragma unroll
          for (int j = 0; j < 2; ++j)
            acc[i][j] = __builtin_amdgcn_mfma_f32_16x16x32_bf16(af[i], bf[j], acc[i][j], 0, 0, 0);
      }
      __syncthreads();
    }

#pragma unroll
    for (int i = 0; i < 4; ++i)
#pragma unroll
      for (int j = 0; j < 2; ++j) {
        const int col = n0 + wn * 32 + j * 16 + l15;
        const float bv = b4[col];
#pragma unroll
        for (int r = 0; r < 4; ++r) {
          const int row = m0 + wm * 64 + i * 16 + quad * 4 + r;
          out[(size_t)row * 512 + col] = acc[i][j][r] + bv;
        }
      }
    return;
  }

  // ================= pairwise role =================
  const int q = blockIdx.x - 512;   // 0..335
  const int cls = q / 21;
  int p = q - cls * 21, ti = 0, cnt = 6;
  while (p >= cnt) { p -= cnt; ++ti; --cnt; }   // block-uniform scalar decode
  const int tj = ti + p;

  const int start = offs[cls];
  const int n = offs[cls + 1] - start;
  if (ti * 128 >= n || tj * 128 >= n) return;

  constexpr int LDA = 66;
  u16* Li = uni;                    // 128*66*2 = 16896 B
  u16* Lj = uni + 128 * LDA;        // +16896 B
  float* sqI = (float*)(uni + 2 * 128 * LDA);       // 512 B
  float* sqJ = sqI + 128;                            // 512 B
  float* red4 = sqJ + 128;                           // 16 B

  for (int e = tid; e < 2048; e += 256) {
    const int t = e >> 10;
    const int row = (e >> 3) & 127;
    const int ch = e & 7;
    const int g = (t ? tj : ti) * 128 + row;
    short8 v = (short8)0;
    if (g < n) {
      v = *(const short8*)(Ebf + (size_t)idx[start + g] * EMBN + ch * 8);
      if (ch == 0) { v[0] = 0; v[1] = 0; }
    }
    *(short8*)((t ? Lj : Li) + row * LDA + ch * 8) = v;
  }
  {
    const int t = tid >> 7, row = tid & 127;
    const int g = (t ? tj : ti) * 128 + row;
    (t ? sqJ : sqI)[row] = (g < n) ? sqrow[idx[start + g]] : 0.f;
  }
  __syncthreads();

  const int wm = wave >> 1, wn = wave & 1;

  floatx4 acc[4][4];
#pragma unroll
  for (int i = 0; i < 4; ++i)
#pragma unroll
    for (int j = 0; j < 4; ++j) acc[i][j] = (floatx4){0.f, 0.f, 0.f, 0.f};

#pragma unroll
  for (int ks = 0; ks < 2; ++ks) {
    short8 af[4], bf[4];
#pragma unroll
    for (int i = 0; i < 4; ++i)
      af[i] = *(const short8*)(Li + (wm * 64 + i * 16 + l15) * LDA + ks * 32 + quad * 8);
#pragma unroll
    for (int j = 0; j < 4; ++j)
      bf[j] = *(const short8*)(Lj + (wn * 64 + j * 16 + l15) * LDA + ks * 32 + quad * 8);
#pragma unroll
    for (int i = 0; i < 4; ++i)
#pragma unroll
      for (int j = 0; j < 4; ++j)
        acc[i][j] = __builtin_amdgcn_mfma_f32_16x16x32_bf16(af[i], bf[j], acc[i][j], 0, 0, 0);
  }

  float local = 0.f;
#pragma unroll
  for (int i = 0; i < 4; ++i)
#pragma unroll
    for (int j = 0; j < 4; ++j)
#pragma unroll
      for (int r = 0; r < 4; ++r) {
        const int row = wm * 64 + i * 16 + quad * 4 + r;
        const int col = wn * 64 + j * 16 + l15;
        const int gi = ti * 128 + row, gj = tj * 128 + col;
        if (gi < n && gj < n && gi != gj) {
          const float D = (sqI[row] + sqJ[col] - 2.f * acc[i][j][r]) * (1.f / 62.f);
          local += fmaxf(0.f, MARGINF - D);
        }
      }
  if (ti < tj) local *= 2.f;

  for (int o = 32; o > 0; o >>= 1) local += __shfl_xor(local, o);
  if (lane == 0) red4[wave] = local;
  __syncthreads();
  if (tid == 0)
    atomicAdd(pair_sum, red4[0] + red4[1] + red4[2] + red4[3]);
}

__device__ __forceinline__ double block_reduce_d(double v, double* red, int tid) {
  red[tid] = v;
  __syncthreads();
  for (int st = 128; st > 0; st >>= 1) {
    if (tid < st) red[tid] += red[tid + st];
    __syncthreads();
  }
  const double r = red[0];
  __syncthreads();
  return r;
}

// C_sim (factored, no N^2) and C_diff from pair_sum + analytic diagonal.
__global__ __launch_bounds__(256)
void finalize(const float* __restrict__ vsumR, const float* __restrict__ SsumR,
              const int* __restrict__ counts, const float* __restrict__ pair_sum,
              float* __restrict__ out2)
{
  const int tid = threadIdx.x;
  __shared__ double red[256];
  __shared__ float vtot[NCLS * NCONS];   // 992 floats

  for (int i = tid; i < NCLS * NCONS; i += 256) {
    float s = 0.f;
    for (int r = 0; r < NREP; ++r) s += vsumR[r * (NCLS * NCONS) + i];
    vtot[i] = s;
  }
  __syncthreads();

  double v = 0.0;
  if (tid < NCLS) {
    float Sc = 0.f;
    for (int r = 0; r < NREP; ++r) Sc += SsumR[r * NCLS + tid];
    v = (double)Sc * (double)(NROWS - counts[tid]);
  }
  const double t1 = block_reduce_d(v, red, tid);            // sum_c S_c (N - n_c)

  v = 0.0;
  if (tid < NCLS) { const double nc = (double)counts[tid]; v = nc * nc; }
  const double n_same = block_reduce_d(v, red, tid);        // sum n_c^2

  v = 0.0;
  for (int i = tid; i < NCLS * NCONS; i += 256) { const double w = vtot[i]; v += w * w; }
  const double t2 = block_reduce_d(v, red, tid);            // sum_c |v_c|^2

  v = 0.0;
  if (tid < NCONS) {
    double Vk = 0.0;
    for (int c = 0; c < NCLS; ++c) Vk += (double)vtot[c * NCONS + tid];
    v = Vk * Vk;
  }
  const double t3 = block_reduce_d(v, red, tid);            // |V|^2

  if (tid == 0) {
    const double n_diff = (double)NROWS * (double)NROWS - n_same;
    const double sim = 2.0 * t1 - 2.0 * (t3 - t2);
    const double C_sim = sim / 62.0 / (n_diff + 1.0);
    const double C_diff = ((double)pair_sum[0] + (double)NROWS * (double)MARGINF)
                          / (n_same + 1.0);
    out2[0] = (float)C_sim;
    out2[1] = (float)C_diff;
  }
}

// ---------------------------------------------------------------------------
// ws_size ~256 MB. Flat ~36 MB. 4 dispatches (was 5).
// ---------------------------------------------------------------------------
extern "C" void kernel_launch(void* const* d_in, const int* in_sizes, int n_in,
                              void* d_out, int out_size, void* d_ws, size_t ws_size,
                              hipStream_t stream)
{
  const float* x  = (const float*)d_in[0];
  const float* W1 = (const float*)d_in[1];
  const float* b1 = (const float*)d_in[2];
  const float* W2 = (const float*)d_in[3];
  const float* b2 = (const float*)d_in[4];
  const float* W3 = (const float*)d_in[5];
  const float* b3 = (const float*)d_in[6];
  const float* W4 = (const float*)d_in[7];
  const float* b4 = (const float*)d_in[8];
  float* out = (float*)d_out;

  char* ws = (char*)d_ws;
  const size_t KB = 1024, MB = 1ull << 20;
  u16* A0p    = (u16*)(ws + 0);                    // 8 MB packed A
  u16* W1p    = (u16*)(ws + 8 * MB);               // 1 MB
  u16* W2p    = (u16*)(ws + 9 * MB);               // 128 KB
  u16* W3p    = (u16*)(ws + 9 * MB + 128 * KB);    // 128 KB
  u16* W4p    = (u16*)(ws + 9 * MB + 256 * KB);    // 1 MB
  u16* Ebf    = (u16*)(ws + 18 * MB + 256 * KB);   // 1 MB
  int* labels = (int*)(ws + 19 * MB + 256 * KB);   // 32 KB
  int* idx    = (int*)(ws + 19 * MB + 288 * KB);   // 32 KB
  float* sqrow = (float*)(ws + 19 * MB + 320 * KB);// 32 KB
  int* hist32 = (int*)(ws + 19 * MB + 352 * KB);   // 2 KB (plain stores)
  float* slab = (float*)(ws + 19 * MB + 384 * KB); // 96 KB zeroed in prep_all
  int*   counts  = (int*)slab;                     // [0,16)
  int*   offs    = counts + 16;                    // [16,33)
  float* psum    = slab + 64;                      // 1
  float* SsumR   = slab + 128;                     // 16 x 16
  float* vsumR   = slab + 512;                     // 16 x 992 = 15872
  u16* T      = (u16*)(ws + 20 * MB);              // 16 MB (8192 x 1024 bf16)
  (void)in_sizes; (void)n_in; (void)out_size; (void)ws_size;

  prep_all<<<dim3(2630), dim3(256), 0, stream>>>(x, W1, W2, W3, W4,
                                                 A0p, W1p, W2p, W3p, W4p,
                                                 slab, labels, hist32);
  fused123<<<dim3(272), dim3(512), 0, stream>>>(A0p, W1p, b1, W2p, b2, W3p, b3,
                                                labels, hist32, offs, counts, idx,
                                                Ebf, sqrow, vsumR, SsumR, T);
  tail<<<dim3(848), dim3(256), 0, stream>>>(T, W4p, b4, out,
                                            Ebf, sqrow, idx, offs, psum);
  finalize<<<dim3(1), dim3(256), 0, stream>>>(vsumR, SsumR, counts, psum,
                                              out + (size_t)NROWS * DIN);
}

// Round 6
// 165.703 us; speedup vs baseline: 1.0540x; 1.0540x over previous
//
#include <hip/hip_runtime.h>
#include <stdint.h>

// Problem constants
#define NROWS 8192
#define DIN   512
#define HIDN  1024
#define EMBN  64
#define NCONS 62      // EMB - N_EFF
#define NCLS  16
#define MARGINF 0.01f
#define NREP  16      // vsum replication factor (atomic contention /16)

typedef unsigned short u16;
typedef __attribute__((ext_vector_type(8))) short short8;   // 8 bf16 (4 VGPRs)
typedef __attribute__((ext_vector_type(4))) float floatx4;  // 4 fp32 acc

__device__ __forceinline__ u16 f32_to_bf16(float f) {
  union { float f; uint32_t u; } x; x.f = f;
  uint32_t u = x.u;
  uint32_t r = (u + 0x7FFFu + ((u >> 16) & 1u)) >> 16;  // RNE
  return (u16)r;
}

__device__ __forceinline__ float bf16_to_f32(u16 h) {
  union { uint32_t u; float f; } x; x.u = (uint32_t)h << 16;
  return x.f;
}

__device__ __forceinline__ float fast_tanh(float x) {
  float xc = fminf(fmaxf(x, -10.f), 10.f);     // clamp: avoid inf/inf
  float e = __expf(2.f * xc);
  return (e - 1.f) * __builtin_amdgcn_rcpf(e + 1.f);
}

__device__ __forceinline__ void load_lds16(const u16* g, u16* l) {
  __builtin_amdgcn_global_load_lds(
      (const __attribute__((address_space(1))) void*)g,
      (__attribute__((address_space(3))) void*)l, 16, 0, 0);
}

// ---------------------------------------------------------------------------
// Weight pre-pack: W (K x N fp32) -> 1KB tiles [nt][ku], tile = 16 n-rows x
// 32 k. Row r's k-chunk c (8 bf16 = 16B) stored at slot c ^ ((r>>1)&3).
// Direct-global frag read: lane for (row=l15, chunk=q) is l15*4 + (q^((l15>>1)&3)).
// ---------------------------------------------------------------------------
__device__ __forceinline__ void pack_tile(const float* __restrict__ W,
                                          u16* __restrict__ Wp,
                                          int N, int KU, int t, int lane)
{
  const int r = lane >> 2, slot = lane & 3;
  const int c = slot ^ ((r >> 1) & 3);
  const int nt = t / KU, ku = t - nt * KU;
  const int n = nt * 16 + r;
  const int kb = ku * 32 + c * 8;
  short8 v;
#pragma unroll
  for (int j = 0; j < 8; ++j) v[j] = (short)f32_to_bf16(W[(size_t)(kb + j) * N + n]);
  *(short8*)(Wp + ((size_t)t * 64 + lane) * 8) = v;
}

// ---------------------------------------------------------------------------
// One kernel for ALL independent prep:
//   blocks [0,2048): x -> A0p (MFMA-A packed bf16); b<32 also labels + a
//   per-block label histogram (plain stores to hist32[32][16]).
//   [2048,2304): pack W1   [2304,2336): pack W2
//   [2336,2368): pack W3   [2368,2624): pack W4
//   [2624,2630): zero 96KB slab (counts/psum/SsumR/vsumR)
// ---------------------------------------------------------------------------
__global__ __launch_bounds__(256)
void prep_all(const float* __restrict__ x,
              const float* __restrict__ W1, const float* __restrict__ W2,
              const float* __restrict__ W3, const float* __restrict__ W4,
              u16* __restrict__ A0p, u16* __restrict__ W1p,
              u16* __restrict__ W2p, u16* __restrict__ W3p,
              u16* __restrict__ W4p, float* __restrict__ slab,
              int* __restrict__ labels, int* __restrict__ hist32)
{
  __shared__ int hh[NCLS];
  const int b = blockIdx.x;
  const int tid = threadIdx.x;
  const int tl = tid >> 6, lane = tid & 63;
  if (b < 2048) {
    if (b < 32) {
      if (tid < NCLS) hh[tid] = 0;
      const int row = b * 256 + tid;
      const int lab = (int)x[(size_t)row * 513];
      labels[row] = lab;
      __syncthreads();
      atomicAdd(&hh[lab], 1);
      __syncthreads();
      if (tid < NCLS) hist32[b * NCLS + tid] = hh[tid];
    }
    const int t = b * 4 + tl;
    const int rt = t >> 4, ku = t & 15;
    const int r = lane & 15, q = lane >> 4;
    const float* src = x + (size_t)(rt * 16 + r) * 513 + 1 + ku * 32 + q * 8;
    short8 v;
#pragma unroll
    for (int j = 0; j < 8; ++j) v[j] = (short)f32_to_bf16(src[j]);
    *(short8*)(A0p + ((size_t)t * 64 + lane) * 8) = v;
  } else if (b < 2304) {
    pack_tile(W1, W1p, 1024, 16, (b - 2048) * 4 + tl, lane);
  } else if (b < 2336) {
    pack_tile(W2, W2p, 64, 32, (b - 2304) * 4 + tl, lane);
  } else if (b < 2368) {
    pack_tile(W3, W3p, 1024, 2, (b - 2336) * 4 + tl, lane);
  } else if (b < 2624) {
    pack_tile(W4, W4p, 512, 32, (b - 2368) * 4 + tl, lane);
  } else {
    float* dst = slab + (size_t)(b - 2624) * 4096;
    for (int i = tid; i < 4096; i += 256) dst[i] = 0.f;
  }
}

// ---------------------------------------------------------------------------
// FUSED layers 1+2+3 + stats (round-6): 16-ROW blocks for occupancy.
// Grid 528 x 512 threads:
//   blocks [0,16): GROUP-SCATTER role.
//   blocks [16,528): 16 rows each. 8 waves; wave w owns a PRIVATE 128-col
//     slice of HID; B direct from global (L2-resident W1p), layer1 K-loop
//     FULLY UNROLLED (no barriers -> compiler pipelines loads under MFMAs).
//     LDS ~44 KB -> 2 blocks/CU resident = 16 waves/CU (was 77 KB, 1 block,
//     8 waves -> Occupancy 20.6%, MfmaUtil 7%: latency-bound, round-5 PMC).
// ---------------------------------------------------------------------------
__global__ __launch_bounds__(512)
void fused123(const u16* __restrict__ A0p, const u16* __restrict__ W1p,
              const float* __restrict__ b1, const u16* __restrict__ W2p,
              const float* __restrict__ b2, const u16* __restrict__ W3p,
              const float* __restrict__ b3,
              const int* __restrict__ labels, const int* __restrict__ hist32,
              int* __restrict__ offs, int* __restrict__ counts,
              int* __restrict__ idx,
              u16* __restrict__ Ebf, float* __restrict__ sqrow,
              float* __restrict__ vsumR, float* __restrict__ SsumR,
              u16* __restrict__ T)
{
  __shared__ u16 uni[16 * 1032];    // 33 KB: Hc[16][1032] bf16 / Epart[8][16][64] f32
  __shared__ u16 El[16 * 66];       // 2.1 KB
  __shared__ float lv[NCLS][64];    // 4 KB
  __shared__ float lsq[NCLS][64];   // 4 KB
  __shared__ int colsum[NCLS], preblk[NCLS], scur[NCLS];

  const int tid = threadIdx.x;

  if (blockIdx.x < 16) {
    // ---- scatter role ----
    const int sb = blockIdx.x;      // 0..15
    if (tid < NCLS) {
      int s = 0, p = 0;
      for (int b2i = 0; b2i < 32; ++b2i) {
        const int h = hist32[b2i * NCLS + tid];
        s += h;
        if (b2i < sb * 2) p += h;
      }
      colsum[tid] = s;
      preblk[tid] = p;
    }
    __syncthreads();
    if (tid < NCLS) {
      int o = 0;
      for (int c = 0; c < tid; ++c) o += colsum[c];
      scur[tid] = o + preblk[tid];
      if (sb == 0) {
        counts[tid] = colsum[tid];
        offs[tid] = o;
        if (tid == NCLS - 1) offs[NCLS] = o + colsum[NCLS - 1];
      }
    }
    __syncthreads();
    {
      const int row = sb * 512 + tid;
      const int p = atomicAdd(&scur[labels[row]], 1);
      idx[p] = row;
    }
    return;
  }

  // ---- compute role: 16 rows ----
  const int bx = blockIdx.x - 16;   // 0..511
  const int m0 = bx * 16;
  const int rep = blockIdx.x & (NREP - 1);
  const int w = tid >> 6, lane = tid & 63;
  const int quad = lane >> 4, l15 = lane & 15;
  const int lamb = l15 * 4 + (quad ^ ((l15 >> 1) & 3));  // pack-permuted lane

  for (int i = tid; i < NCLS * 64; i += 512) {
    ((float*)lv)[i] = 0.f; ((float*)lsq)[i] = 0.f;
  }

  u16* Hc = uni;                    // [16][1032] bf16
  float* Epart = (float*)uni;       // [8][16][64] f32 (overlay, after barrier 2)

  // ======== layer1: H = tanh(A @ W1 + b1), wave w -> cols [w*128,(w+1)*128)
  // Fully unrolled: 16 A loads + 128 B loads + 128 MFMAs, straight-line,
  // zero barriers -> scheduler pipelines next-step loads under MFMAs.
  floatx4 acc1[8];
#pragma unroll
  for (int jj = 0; jj < 8; ++jj) acc1[jj] = (floatx4){0.f, 0.f, 0.f, 0.f};

#pragma unroll
  for (int s = 0; s < 16; ++s) {
    const short8 af = *(const short8*)(A0p + (size_t)(bx * 16 + s) * 512 + lane * 8);
#pragma unroll
    for (int jj = 0; jj < 8; ++jj) {
      const short8 bf = *(const short8*)(W1p + (size_t)((w * 8 + jj) * 16 + s) * 512 + lamb * 8);
      acc1[jj] = __builtin_amdgcn_mfma_f32_16x16x32_bf16(af, bf, acc1[jj], 0, 0, 0);
    }
  }
#pragma unroll
  for (int jj = 0; jj < 8; ++jj) {
    const int col = w * 128 + jj * 16 + l15;
    const float bv = b1[col];
#pragma unroll
    for (int r = 0; r < 4; ++r)
      Hc[(quad * 4 + r) * 1032 + col] = f32_to_bf16(fast_tanh(acc1[jj][r] + bv));
  }
  __syncthreads();   // (1) Hc complete

  // ======== layer2: E = H @ W2 (16x64), K-split: wave w sums H cols [w*128,+128)
  floatx4 acc2[4];
#pragma unroll
  for (int nt = 0; nt < 4; ++nt) acc2[nt] = (floatx4){0.f, 0.f, 0.f, 0.f};

#pragma unroll
  for (int kk = 0; kk < 4; ++kk) {
    const int ku = w * 4 + kk;
    const short8 af = *(const short8*)(Hc + l15 * 1032 + ku * 32 + quad * 8);
#pragma unroll
    for (int nt = 0; nt < 4; ++nt) {
      const short8 bf = *(const short8*)(W2p + (size_t)(nt * 32 + ku) * 512 + lamb * 8);
      acc2[nt] = __builtin_amdgcn_mfma_f32_16x16x32_bf16(af, bf, acc2[nt], 0, 0, 0);
    }
  }
  __syncthreads();   // (2) all Hc reads done -> overlay safe

#pragma unroll
  for (int nt = 0; nt < 4; ++nt)
#pragma unroll
    for (int r = 0; r < 4; ++r)
      Epart[((size_t)w * 16 + quad * 4 + r) * 64 + nt * 16 + l15] = acc2[nt][r];
  __syncthreads();   // (3) partials complete

  // ======== reduce 8 partials + b2 -> Ebf/El + stats (all 8 waves, 2 rows each)
  {
    const float bv2 = b2[lane];
    for (int r = 0; r < 2; ++r) {
      const int row = w * 2 + r;
      const int grow = m0 + row;
      const int c = labels[grow];
      float acc = bv2;
#pragma unroll
      for (int p = 0; p < 8; ++p)
        acc += Epart[((size_t)p * 16 + row) * 64 + lane];
      const u16 h = f32_to_bf16(acc);
      Ebf[(size_t)grow * 64 + lane] = h;
      El[row * 66 + lane] = h;
      float v = bf16_to_f32(h);
      if (lane < 2) v = 0.f;
      const float v2 = v * v;
      atomicAdd(&lv[c][lane], v);
      atomicAdd(&lsq[c][lane], v2);
      float s = v2;
      for (int o = 32; o > 0; o >>= 1) s += __shfl_xor(s, o);
      if (lane == 0) sqrow[grow] = s;
    }
  }
  __syncthreads();   // (4) El + lv/lsq complete

  // flush per-class sums to replicated global accumulators
  for (int i = tid; i < NCLS * 64; i += 512) {
    const int c = i >> 6, k = i & 63;
    if (k >= 2) atomicAdd(&vsumR[rep * (NCLS * NCONS) + c * NCONS + k - 2], lv[c][k]);
  }
  if (tid < NCLS) {
    float s = 0.f;
    for (int k = 0; k < 64; ++k) s += lsq[tid][k];
    atomicAdd(&SsumR[rep * NCLS + tid], s);
  }

  // ======== layer3: T = tanh(E @ W3 + b3), wave w -> cols [w*128,(w+1)*128)
  floatx4 acc3[8];
#pragma unroll
  for (int jj = 0; jj < 8; ++jj) acc3[jj] = (floatx4){0.f, 0.f, 0.f, 0.f};

#pragma unroll
  for (int kk = 0; kk < 2; ++kk) {
    const short8 af = *(const short8*)(El + l15 * 66 + kk * 32 + quad * 8);
#pragma unroll
    for (int jj = 0; jj < 8; ++jj) {
      const int nt = w * 8 + jj;
      const short8 bf = *(const short8*)(W3p + (size_t)(nt * 2 + kk) * 512 + lamb * 8);
      acc3[jj] = __builtin_amdgcn_mfma_f32_16x16x32_bf16(af, bf, acc3[jj], 0, 0, 0);
    }
  }
#pragma unroll
  for (int jj = 0; jj < 8; ++jj) {
    const int col = w * 128 + jj * 16 + l15;
    const float bv3 = b3[col];
#pragma unroll
    for (int r = 0; r < 4; ++r)
      T[(size_t)(m0 + quad * 4 + r) * 1024 + col] =
          f32_to_bf16(fast_tanh(acc3[jj][r] + bv3));
  }
}

// ---------------------------------------------------------------------------
// MERGED tail: blocks [0,512) = layer4 GEMM (out = T @ W4 + b4, 128x64 tile,
// XCD-aware remap), blocks [512,848) = same-class pairwise hinge (128x128
// pair-tiles). Union LDS 48 KB.
// ---------------------------------------------------------------------------
__global__ __launch_bounds__(256)
void tail(const u16* __restrict__ T, const u16* __restrict__ W4p,
          const float* __restrict__ b4, float* __restrict__ out,
          const u16* __restrict__ Ebf, const float* __restrict__ sqrow,
          const int* __restrict__ idx, const int* __restrict__ offs,
          float* __restrict__ pair_sum)
{
  __shared__ u16 uni[24576];        // 48 KB union
  const int tid = threadIdx.x, wave = tid >> 6, lane = tid & 63;
  const int quad = lane >> 4, l15 = lane & 15;

  if (blockIdx.x < 512) {
    // ================= gemm4 role =================
    u16* lA = uni;                  // [2][16*512] = 32 KB
    u16* lBb = uni + 16384;         // [2][8*512]  = 16 KB
    const int wm = wave >> 1, wn = wave & 1;
    const int xslot = (l15 >> 1) & 3;
    const int lin = blockIdx.x;     // 0..511
    const int n0 = (lin >> 6) * 64;    // 8 n-tiles
    const int m0 = (lin & 63) * 128;   // 64 m-panels; same panel -> same lin%8
    const int srow = lane >> 2;                        // row within 16-row unit
    const int schunk = (lane & 3) ^ ((lane >> 3) & 3); // XOR chunk swizzle

    auto stage = [&](int s, int buf) {
#pragma unroll
      for (int q = 0; q < 6; ++q) {
        const int u = wave + q * 4;
        if (u < 16) {
          const int rg = u >> 1, kh = u & 1;
          load_lds16(T + (size_t)(m0 + rg * 16 + srow) * 1024 + s * 64 + kh * 32 + schunk * 8,
                     lA + buf * 8192 + u * 512 + lane * 8);
        } else {
          const int v = u - 16, nt = v >> 1, kh = v & 1;
          load_lds16(W4p + (size_t)(((n0 >> 4) + nt) * 32 + s * 2 + kh) * 512 + lane * 8,
                     lBb + buf * 4096 + v * 512 + lane * 8);
        }
      }
    };

    stage(0, 0);
    __syncthreads();

    floatx4 acc[4][2];
#pragma unroll
    for (int i = 0; i < 4; ++i)
#pragma unroll
      for (int j = 0; j < 2; ++j) acc[i][j] = (floatx4){0.f, 0.f, 0.f, 0.f};

    for (int s = 0; s < 16; ++s) {
      const int p = s & 1;
      if (s < 15) stage(s + 1, 1 - p);
#pragma unroll
      for (int kk = 0; kk < 2; ++kk) {
        short8 af[4], bf[2];
#pragma unroll
        for (int i = 0; i < 4; ++i)
          af[i] = *(const short8*)(lA + p * 8192 + ((wm * 4 + i) * 2 + kk) * 512
                                   + l15 * 32 + ((quad ^ xslot) << 3));
#pragma unroll
        for (int j = 0; j < 2; ++j)
          bf[j] = *(const short8*)(lBb + p * 4096 + ((wn * 2 + j) * 2 + kk) * 512
                                   + l15 * 32 + ((quad ^ xslot) << 3));
#pragma unroll
        for (int i = 0; i < 4; ++i)
#pragma unroll
          for (int j = 0; j < 2; ++j)
            acc[i][j] = __builtin_amdgcn_mfma_f32_16x16x32_bf16(af[i], bf[j], acc[i][j], 0, 0, 0);
      }
      __syncthreads();
    }

#pragma unroll
    for (int i = 0; i < 4; ++i)
#pragma unroll
      for (int j = 0; j < 2; ++j) {
        const int col = n0 + wn * 32 + j * 16 + l15;
        const float bv = b4[col];
#pragma unroll
        for (int r = 0; r < 4; ++r) {
          const int row = m0 + wm * 64 + i * 16 + quad * 4 + r;
          out[(size_t)row * 512 + col] = acc[i][j][r] + bv;
        }
      }
    return;
  }

  // ================= pairwise role =================
  const int q = blockIdx.x - 512;   // 0..335
  const int cls = q / 21;
  int p = q - cls * 21, ti = 0, cnt = 6;
  while (p >= cnt) { p -= cnt; ++ti; --cnt; }   // block-uniform scalar decode
  const int tj = ti + p;

  const int start = offs[cls];
  const int n = offs[cls + 1] - start;
  if (ti * 128 >= n || tj * 128 >= n) return;

  constexpr int LDA = 66;
  u16* Li = uni;                    // 128*66*2 = 16896 B
  u16* Lj = uni + 128 * LDA;        // +16896 B
  float* sqI = (float*)(uni + 2 * 128 * LDA);       // 512 B
  float* sqJ = sqI + 128;                            // 512 B
  float* red4 = sqJ + 128;                           // 16 B

  for (int e = tid; e < 2048; e += 256) {
    const int t = e >> 10;
    const int row = (e >> 3) & 127;
    const int ch = e & 7;
    const int g = (t ? tj : ti) * 128 + row;
    short8 v = (short8)0;
    if (g < n) {
      v = *(const short8*)(Ebf + (size_t)idx[start + g] * EMBN + ch * 8);
      if (ch == 0) { v[0] = 0; v[1] = 0; }
    }
    *(short8*)((t ? Lj : Li) + row * LDA + ch * 8) = v;
  }
  {
    const int t = tid >> 7, row = tid & 127;
    const int g = (t ? tj : ti) * 128 + row;
    (t ? sqJ : sqI)[row] = (g < n) ? sqrow[idx[start + g]] : 0.f;
  }
  __syncthreads();

  const int wm = wave >> 1, wn = wave & 1;

  floatx4 acc[4][4];
#pragma unroll
  for (int i = 0; i < 4; ++i)
#pragma unroll
    for (int j = 0; j < 4; ++j) acc[i][j] = (floatx4){0.f, 0.f, 0.f, 0.f};

#pragma unroll
  for (int ks = 0; ks < 2; ++ks) {
    short8 af[4], bf[4];
#pragma unroll
    for (int i = 0; i < 4; ++i)
      af[i] = *(const short8*)(Li + (wm * 64 + i * 16 + l15) * LDA + ks * 32 + quad * 8);
#pragma unroll
    for (int j = 0; j < 4; ++j)
      bf[j] = *(const short8*)(Lj + (wn * 64 + j * 16 + l15) * LDA + ks * 32 + quad * 8);
#pragma unroll
    for (int i = 0; i < 4; ++i)
#pragma unroll
      for (int j = 0; j < 4; ++j)
        acc[i][j] = __builtin_amdgcn_mfma_f32_16x16x32_bf16(af[i], bf[j], acc[i][j], 0, 0, 0);
  }

  float local = 0.f;
#pragma unroll
  for (int i = 0; i < 4; ++i)
#pragma unroll
    for (int j = 0; j < 4; ++j)
#pragma unroll
      for (int r = 0; r < 4; ++r) {
        const int row = wm * 64 + i * 16 + quad * 4 + r;
        const int col = wn * 64 + j * 16 + l15;
        const int gi = ti * 128 + row, gj = tj * 128 + col;
        if (gi < n && gj < n && gi != gj) {
          const float D = (sqI[row] + sqJ[col] - 2.f * acc[i][j][r]) * (1.f / 62.f);
          local += fmaxf(0.f, MARGINF - D);
        }
      }
  if (ti < tj) local *= 2.f;

  for (int o = 32; o > 0; o >>= 1) local += __shfl_xor(local, o);
  if (lane == 0) red4[wave] = local;
  __syncthreads();
  if (tid == 0)
    atomicAdd(pair_sum, red4[0] + red4[1] + red4[2] + red4[3]);
}

__device__ __forceinline__ double block_reduce_d(double v, double* red, int tid) {
  red[tid] = v;
  __syncthreads();
  for (int st = 128; st > 0; st >>= 1) {
    if (tid < st) red[tid] += red[tid + st];
    __syncthreads();
  }
  const double r = red[0];
  __syncthreads();
  return r;
}

// C_sim (factored, no N^2) and C_diff from pair_sum + analytic diagonal.
__global__ __launch_bounds__(256)
void finalize(const float* __restrict__ vsumR, const float* __restrict__ SsumR,
              const int* __restrict__ counts, const float* __restrict__ pair_sum,
              float* __restrict__ out2)
{
  const int tid = threadIdx.x;
  __shared__ double red[256];
  __shared__ float vtot[NCLS * NCONS];   // 992 floats

  for (int i = tid; i < NCLS * NCONS; i += 256) {
    float s = 0.f;
    for (int r = 0; r < NREP; ++r) s += vsumR[r * (NCLS * NCONS) + i];
    vtot[i] = s;
  }
  __syncthreads();

  double v = 0.0;
  if (tid < NCLS) {
    float Sc = 0.f;
    for (int r = 0; r < NREP; ++r) Sc += SsumR[r * NCLS + tid];
    v = (double)Sc * (double)(NROWS - counts[tid]);
  }
  const double t1 = block_reduce_d(v, red, tid);            // sum_c S_c (N - n_c)

  v = 0.0;
  if (tid < NCLS) { const double nc = (double)counts[tid]; v = nc * nc; }
  const double n_same = block_reduce_d(v, red, tid);        // sum n_c^2

  v = 0.0;
  for (int i = tid; i < NCLS * NCONS; i += 256) { const double w = vtot[i]; v += w * w; }
  const double t2 = block_reduce_d(v, red, tid);            // sum_c |v_c|^2

  v = 0.0;
  if (tid < NCONS) {
    double Vk = 0.0;
    for (int c = 0; c < NCLS; ++c) Vk += (double)vtot[c * NCONS + tid];
    v = Vk * Vk;
  }
  const double t3 = block_reduce_d(v, red, tid);            // |V|^2

  if (tid == 0) {
    const double n_diff = (double)NROWS * (double)NROWS - n_same;
    const double sim = 2.0 * t1 - 2.0 * (t3 - t2);
    const double C_sim = sim / 62.0 / (n_diff + 1.0);
    const double C_diff = ((double)pair_sum[0] + (double)NROWS * (double)MARGINF)
                          / (n_same + 1.0);
    out2[0] = (float)C_sim;
    out2[1] = (float)C_diff;
  }
}

// ---------------------------------------------------------------------------
// ws_size ~256 MB. Flat ~36 MB. 4 dispatches.
// ---------------------------------------------------------------------------
extern "C" void kernel_launch(void* const* d_in, const int* in_sizes, int n_in,
                              void* d_out, int out_size, void* d_ws, size_t ws_size,
                              hipStream_t stream)
{
  const float* x  = (const float*)d_in[0];
  const float* W1 = (const float*)d_in[1];
  const float* b1 = (const float*)d_in[2];
  const float* W2 = (const float*)d_in[3];
  const float* b2 = (const float*)d_in[4];
  const float* W3 = (const float*)d_in[5];
  const float* b3 = (const float*)d_in[6];
  const float* W4 = (const float*)d_in[7];
  const float* b4 = (const float*)d_in[8];
  float* out = (float*)d_out;

  char* ws = (char*)d_ws;
  const size_t KB = 1024, MB = 1ull << 20;
  u16* A0p    = (u16*)(ws + 0);                    // 8 MB packed A
  u16* W1p    = (u16*)(ws + 8 * MB);               // 1 MB
  u16* W2p    = (u16*)(ws + 9 * MB);               // 128 KB
  u16* W3p    = (u16*)(ws + 9 * MB + 128 * KB);    // 128 KB
  u16* W4p    = (u16*)(ws + 9 * MB + 256 * KB);    // 1 MB
  u16* Ebf    = (u16*)(ws + 18 * MB + 256 * KB);   // 1 MB
  int* labels = (int*)(ws + 19 * MB + 256 * KB);   // 32 KB
  int* idx    = (int*)(ws + 19 * MB + 288 * KB);   // 32 KB
  float* sqrow = (float*)(ws + 19 * MB + 320 * KB);// 32 KB
  int* hist32 = (int*)(ws + 19 * MB + 352 * KB);   // 2 KB (plain stores)
  float* slab = (float*)(ws + 19 * MB + 384 * KB); // 96 KB zeroed in prep_all
  int*   counts  = (int*)slab;                     // [0,16)
  int*   offs    = counts + 16;                    // [16,33)
  float* psum    = slab + 64;                      // 1
  float* SsumR   = slab + 128;                     // 16 x 16
  float* vsumR   = slab + 512;                     // 16 x 992 = 15872
  u16* T      = (u16*)(ws + 20 * MB);              // 16 MB (8192 x 1024 bf16)
  (void)in_sizes; (void)n_in; (void)out_size; (void)ws_size;

  prep_all<<<dim3(2630), dim3(256), 0, stream>>>(x, W1, W2, W3, W4,
                                                 A0p, W1p, W2p, W3p, W4p,
                                                 slab, labels, hist32);
  fused123<<<dim3(528), dim3(512), 0, stream>>>(A0p, W1p, b1, W2p, b2, W3p, b3,
                                                labels, hist32, offs, counts, idx,
                                                Ebf, sqrow, vsumR, SsumR, T);
  tail<<<dim3(848), dim3(256), 0, stream>>>(T, W4p, b4, out,
                                            Ebf, sqrow, idx, offs, psum);
  finalize<<<dim3(1), dim3(256), 0, stream>>>(vsumR, SsumR, counts, psum,
                                              out + (size_t)NROWS * DIN);
}

// Round 7
// 156.702 us; speedup vs baseline: 1.1146x; 1.0574x over previous
//
#include <hip/hip_runtime.h>
#include <stdint.h>

// Problem constants
#define NROWS 8192
#define DIN   512
#define HIDN  1024
#define EMBN  64
#define NCONS 62      // EMB - N_EFF
#define NCLS  16
#define MARGINF 0.01f
#define NREP  16      // vsum replication factor (atomic contention /16)

typedef unsigned short u16;
typedef __attribute__((ext_vector_type(8))) short short8;   // 8 bf16 (4 VGPRs)
typedef __attribute__((ext_vector_type(4))) float floatx4;  // 4 fp32 acc

__device__ __forceinline__ u16 f32_to_bf16(float f) {
  union { float f; uint32_t u; } x; x.f = f;
  uint32_t u = x.u;
  uint32_t r = (u + 0x7FFFu + ((u >> 16) & 1u)) >> 16;  // RNE
  return (u16)r;
}

__device__ __forceinline__ float bf16_to_f32(u16 h) {
  union { uint32_t u; float f; } x; x.u = (uint32_t)h << 16;
  return x.f;
}

__device__ __forceinline__ float fast_tanh(float x) {
  float xc = fminf(fmaxf(x, -10.f), 10.f);     // clamp: avoid inf/inf
  float e = __expf(2.f * xc);
  return (e - 1.f) * __builtin_amdgcn_rcpf(e + 1.f);
}

__device__ __forceinline__ void load_lds16(const u16* g, u16* l) {
  __builtin_amdgcn_global_load_lds(
      (const __attribute__((address_space(1))) void*)g,
      (__attribute__((address_space(3))) void*)l, 16, 0, 0);
}

// ---------------------------------------------------------------------------
// Weight pre-pack: W (K x N fp32) -> 1KB tiles [nt][ku], tile = 16 n-rows x
// 32 k. Row r's k-chunk c (8 bf16 = 16B) stored at slot c ^ ((r>>1)&3).
// Direct-global frag read: lane for (row=l15, chunk=q) is l15*4 + (q^((l15>>1)&3)).
// ---------------------------------------------------------------------------
__device__ __forceinline__ void pack_tile(const float* __restrict__ W,
                                          u16* __restrict__ Wp,
                                          int N, int KU, int t, int lane)
{
  const int r = lane >> 2, slot = lane & 3;
  const int c = slot ^ ((r >> 1) & 3);
  const int nt = t / KU, ku = t - nt * KU;
  const int n = nt * 16 + r;
  const int kb = ku * 32 + c * 8;
  short8 v;
#pragma unroll
  for (int j = 0; j < 8; ++j) v[j] = (short)f32_to_bf16(W[(size_t)(kb + j) * N + n]);
  *(short8*)(Wp + ((size_t)t * 64 + lane) * 8) = v;
}

// ---------------------------------------------------------------------------
// One kernel for ALL independent prep:
//   blocks [0,2048): x -> A0p (MFMA-A packed bf16); b<32 also labels + a
//   per-block label histogram (plain stores to hist32[32][16]).
//   [2048,2304): pack W1   [2304,2336): pack W2
//   [2336,2368): pack W3   [2368,2624): pack W4
//   [2624,2630): zero 96KB slab (counts/psum/SsumR/vsumR)
// ---------------------------------------------------------------------------
__global__ __launch_bounds__(256)
void prep_all(const float* __restrict__ x,
              const float* __restrict__ W1, const float* __restrict__ W2,
              const float* __restrict__ W3, const float* __restrict__ W4,
              u16* __restrict__ A0p, u16* __restrict__ W1p,
              u16* __restrict__ W2p, u16* __restrict__ W3p,
              u16* __restrict__ W4p, float* __restrict__ slab,
              int* __restrict__ labels, int* __restrict__ hist32)
{
  __shared__ int hh[NCLS];
  const int b = blockIdx.x;
  const int tid = threadIdx.x;
  const int tl = tid >> 6, lane = tid & 63;
  if (b < 2048) {
    if (b < 32) {
      if (tid < NCLS) hh[tid] = 0;
      const int row = b * 256 + tid;
      const int lab = (int)x[(size_t)row * 513];
      labels[row] = lab;
      __syncthreads();
      atomicAdd(&hh[lab], 1);
      __syncthreads();
      if (tid < NCLS) hist32[b * NCLS + tid] = hh[tid];
    }
    const int t = b * 4 + tl;
    const int rt = t >> 4, ku = t & 15;
    const int r = lane & 15, q = lane >> 4;
    const float* src = x + (size_t)(rt * 16 + r) * 513 + 1 + ku * 32 + q * 8;
    short8 v;
#pragma unroll
    for (int j = 0; j < 8; ++j) v[j] = (short)f32_to_bf16(src[j]);
    *(short8*)(A0p + ((size_t)t * 64 + lane) * 8) = v;
  } else if (b < 2304) {
    pack_tile(W1, W1p, 1024, 16, (b - 2048) * 4 + tl, lane);
  } else if (b < 2336) {
    pack_tile(W2, W2p, 64, 32, (b - 2304) * 4 + tl, lane);
  } else if (b < 2368) {
    pack_tile(W3, W3p, 1024, 2, (b - 2336) * 4 + tl, lane);
  } else if (b < 2624) {
    pack_tile(W4, W4p, 512, 32, (b - 2368) * 4 + tl, lane);
  } else {
    float* dst = slab + (size_t)(b - 2624) * 4096;
    for (int i = tid; i < 4096; i += 256) dst[i] = 0.f;
  }
}

// ---------------------------------------------------------------------------
// FUSED layers 1+2+3 + stats (round-7): 16-row blocks (grid 528, 2/CU) +
// REGISTER DOUBLE-BUFFERED layer1: bfb[2][8]+afb[2] ping-pong keeps 9 L2
// loads in flight per wave (round-6 PMC: VGPR=44 -> ~2 in flight -> 8%
// MfmaUtil, latency-bound). __launch_bounds__(512,4) pins VGPR<=128 so
// 2 blocks/CU (16 waves) survives the added register pressure.
// ---------------------------------------------------------------------------
__global__ __launch_bounds__(512, 4)
void fused123(const u16* __restrict__ A0p, const u16* __restrict__ W1p,
              const float* __restrict__ b1, const u16* __restrict__ W2p,
              const float* __restrict__ b2, const u16* __restrict__ W3p,
              const float* __restrict__ b3,
              const int* __restrict__ labels, const int* __restrict__ hist32,
              int* __restrict__ offs, int* __restrict__ counts,
              int* __restrict__ idx,
              u16* __restrict__ Ebf, float* __restrict__ sqrow,
              float* __restrict__ vsumR, float* __restrict__ SsumR,
              u16* __restrict__ T)
{
  __shared__ u16 uni[16 * 1032];    // 33 KB: Hc[16][1032] bf16 / Epart[8][16][64] f32
  __shared__ u16 El[16 * 66];       // 2.1 KB
  __shared__ float lv[NCLS][64];    // 4 KB
  __shared__ float lsq[NCLS][64];   // 4 KB
  __shared__ int colsum[NCLS], preblk[NCLS], scur[NCLS];

  const int tid = threadIdx.x;

  if (blockIdx.x < 16) {
    // ---- scatter role ----
    const int sb = blockIdx.x;      // 0..15
    if (tid < NCLS) {
      int s = 0, p = 0;
      for (int b2i = 0; b2i < 32; ++b2i) {
        const int h = hist32[b2i * NCLS + tid];
        s += h;
        if (b2i < sb * 2) p += h;
      }
      colsum[tid] = s;
      preblk[tid] = p;
    }
    __syncthreads();
    if (tid < NCLS) {
      int o = 0;
      for (int c = 0; c < tid; ++c) o += colsum[c];
      scur[tid] = o + preblk[tid];
      if (sb == 0) {
        counts[tid] = colsum[tid];
        offs[tid] = o;
        if (tid == NCLS - 1) offs[NCLS] = o + colsum[NCLS - 1];
      }
    }
    __syncthreads();
    {
      const int row = sb * 512 + tid;
      const int p = atomicAdd(&scur[labels[row]], 1);
      idx[p] = row;
    }
    return;
  }

  // ---- compute role: 16 rows ----
  const int bx = blockIdx.x - 16;   // 0..511
  const int m0 = bx * 16;
  const int rep = blockIdx.x & (NREP - 1);
  const int w = tid >> 6, lane = tid & 63;
  const int quad = lane >> 4, l15 = lane & 15;
  const int lamb = l15 * 4 + (quad ^ ((l15 >> 1) & 3));  // pack-permuted lane

  for (int i = tid; i < NCLS * 64; i += 512) {
    ((float*)lv)[i] = 0.f; ((float*)lsq)[i] = 0.f;
  }

  u16* Hc = uni;                    // [16][1032] bf16
  float* Epart = (float*)uni;       // [8][16][64] f32 (overlay, after barrier 2)

  // ======== layer1: H = tanh(A @ W1 + b1), wave w -> cols [w*128,(w+1)*128)
  // Register-pipelined: loads for step s+1 issued before MFMAs of step s.
  // All buffer indices compile-time constant after full unroll (no scratch).
  const u16* Wbase = W1p + (size_t)(w * 8) * 16 * 512 + lamb * 8;
  const u16* Abase = A0p + (size_t)(bx * 16) * 512 + lane * 8;

  floatx4 acc1[8];
#pragma unroll
  for (int jj = 0; jj < 8; ++jj) acc1[jj] = (floatx4){0.f, 0.f, 0.f, 0.f};

  short8 bfb[2][8];
  short8 afb[2];
  afb[0] = *(const short8*)(Abase);
#pragma unroll
  for (int jj = 0; jj < 8; ++jj)
    bfb[0][jj] = *(const short8*)(Wbase + (size_t)(jj * 16) * 512);

#pragma unroll
  for (int s = 0; s < 16; ++s) {
    const int cur = s & 1, nxt = cur ^ 1;
    if (s < 15) {
      afb[nxt] = *(const short8*)(Abase + (size_t)(s + 1) * 512);
#pragma unroll
      for (int jj = 0; jj < 8; ++jj)
        bfb[nxt][jj] = *(const short8*)(Wbase + (size_t)(jj * 16 + s + 1) * 512);
    }
#pragma unroll
    for (int jj = 0; jj < 8; ++jj)
      acc1[jj] = __builtin_amdgcn_mfma_f32_16x16x32_bf16(afb[cur], bfb[cur][jj], acc1[jj], 0, 0, 0);
  }

#pragma unroll
  for (int jj = 0; jj < 8; ++jj) {
    const int col = w * 128 + jj * 16 + l15;
    const float bv = b1[col];
#pragma unroll
    for (int r = 0; r < 4; ++r)
      Hc[(quad * 4 + r) * 1032 + col] = f32_to_bf16(fast_tanh(acc1[jj][r] + bv));
  }
  __syncthreads();   // (1) Hc complete

  // ======== layer2: E = H @ W2 (16x64), K-split: wave w sums H cols [w*128,+128)
  floatx4 acc2[4];
#pragma unroll
  for (int nt = 0; nt < 4; ++nt) acc2[nt] = (floatx4){0.f, 0.f, 0.f, 0.f};

#pragma unroll
  for (int kk = 0; kk < 4; ++kk) {
    const int ku = w * 4 + kk;
    const short8 af = *(const short8*)(Hc + l15 * 1032 + ku * 32 + quad * 8);
#pragma unroll
    for (int nt = 0; nt < 4; ++nt) {
      const short8 bf = *(const short8*)(W2p + (size_t)(nt * 32 + ku) * 512 + lamb * 8);
      acc2[nt] = __builtin_amdgcn_mfma_f32_16x16x32_bf16(af, bf, acc2[nt], 0, 0, 0);
    }
  }
  __syncthreads();   // (2) all Hc reads done -> overlay safe

#pragma unroll
  for (int nt = 0; nt < 4; ++nt)
#pragma unroll
    for (int r = 0; r < 4; ++r)
      Epart[((size_t)w * 16 + quad * 4 + r) * 64 + nt * 16 + l15] = acc2[nt][r];
  __syncthreads();   // (3) partials complete

  // ======== reduce 8 partials + b2 -> Ebf/El + stats (all 8 waves, 2 rows each)
  {
    const float bv2 = b2[lane];
    for (int r = 0; r < 2; ++r) {
      const int row = w * 2 + r;
      const int grow = m0 + row;
      const int c = labels[grow];
      float acc = bv2;
#pragma unroll
      for (int p = 0; p < 8; ++p)
        acc += Epart[((size_t)p * 16 + row) * 64 + lane];
      const u16 h = f32_to_bf16(acc);
      Ebf[(size_t)grow * 64 + lane] = h;
      El[row * 66 + lane] = h;
      float v = bf16_to_f32(h);
      if (lane < 2) v = 0.f;
      const float v2 = v * v;
      atomicAdd(&lv[c][lane], v);
      atomicAdd(&lsq[c][lane], v2);
      float s = v2;
      for (int o = 32; o > 0; o >>= 1) s += __shfl_xor(s, o);
      if (lane == 0) sqrow[grow] = s;
    }
  }
  __syncthreads();   // (4) El + lv/lsq complete

  // flush per-class sums to replicated global accumulators
  for (int i = tid; i < NCLS * 64; i += 512) {
    const int c = i >> 6, k = i & 63;
    if (k >= 2) atomicAdd(&vsumR[rep * (NCLS * NCONS) + c * NCONS + k - 2], lv[c][k]);
  }
  if (tid < NCLS) {
    float s = 0.f;
    for (int k = 0; k < 64; ++k) s += lsq[tid][k];
    atomicAdd(&SsumR[rep * NCLS + tid], s);
  }

  // ======== layer3: T = tanh(E @ W3 + b3), wave w -> cols [w*128,(w+1)*128)
  floatx4 acc3[8];
#pragma unroll
  for (int jj = 0; jj < 8; ++jj) acc3[jj] = (floatx4){0.f, 0.f, 0.f, 0.f};

#pragma unroll
  for (int kk = 0; kk < 2; ++kk) {
    const short8 af = *(const short8*)(El + l15 * 66 + kk * 32 + quad * 8);
#pragma unroll
    for (int jj = 0; jj < 8; ++jj) {
      const int nt = w * 8 + jj;
      const short8 bf = *(const short8*)(W3p + (size_t)(nt * 2 + kk) * 512 + lamb * 8);
      acc3[jj] = __builtin_amdgcn_mfma_f32_16x16x32_bf16(af, bf, acc3[jj], 0, 0, 0);
    }
  }
#pragma unroll
  for (int jj = 0; jj < 8; ++jj) {
    const int col = w * 128 + jj * 16 + l15;
    const float bv3 = b3[col];
#pragma unroll
    for (int r = 0; r < 4; ++r)
      T[(size_t)(m0 + quad * 4 + r) * 1024 + col] =
          f32_to_bf16(fast_tanh(acc3[jj][r] + bv3));
  }
}

// ---------------------------------------------------------------------------
// MERGED tail: blocks [0,512) = layer4 GEMM (out = T @ W4 + b4, 128x64 tile,
// XCD-aware remap), blocks [512,848) = same-class pairwise hinge (128x128
// pair-tiles). Union LDS 48 KB.
// ---------------------------------------------------------------------------
__global__ __launch_bounds__(256)
void tail(const u16* __restrict__ T, const u16* __restrict__ W4p,
          const float* __restrict__ b4, float* __restrict__ out,
          const u16* __restrict__ Ebf, const float* __restrict__ sqrow,
          const int* __restrict__ idx, const int* __restrict__ offs,
          float* __restrict__ pair_sum)
{
  __shared__ u16 uni[24576];        // 48 KB union
  const int tid = threadIdx.x, wave = tid >> 6, lane = tid & 63;
  const int quad = lane >> 4, l15 = lane & 15;

  if (blockIdx.x < 512) {
    // ================= gemm4 role =================
    u16* lA = uni;                  // [2][16*512] = 32 KB
    u16* lBb = uni + 16384;         // [2][8*512]  = 16 KB
    const int wm = wave >> 1, wn = wave & 1;
    const int xslot = (l15 >> 1) & 3;
    const int lin = blockIdx.x;     // 0..511
    const int n0 = (lin >> 6) * 64;    // 8 n-tiles
    const int m0 = (lin & 63) * 128;   // 64 m-panels; same panel -> same lin%8
    const int srow = lane >> 2;                        // row within 16-row unit
    const int schunk = (lane & 3) ^ ((lane >> 3) & 3); // XOR chunk swizzle

    auto stage = [&](int s, int buf) {
#pragma unroll
      for (int q = 0; q < 6; ++q) {
        const int u = wave + q * 4;
        if (u < 16) {
          const int rg = u >> 1, kh = u & 1;
          load_lds16(T + (size_t)(m0 + rg * 16 + srow) * 1024 + s * 64 + kh * 32 + schunk * 8,
                     lA + buf * 8192 + u * 512 + lane * 8);
        } else {
          const int v = u - 16, nt = v >> 1, kh = v & 1;
          load_lds16(W4p + (size_t)(((n0 >> 4) + nt) * 32 + s * 2 + kh) * 512 + lane * 8,
                     lBb + buf * 4096 + v * 512 + lane * 8);
        }
      }
    };

    stage(0, 0);
    __syncthreads();

    floatx4 acc[4][2];
#pragma unroll
    for (int i = 0; i < 4; ++i)
#pragma unroll
      for (int j = 0; j < 2; ++j) acc[i][j] = (floatx4){0.f, 0.f, 0.f, 0.f};

    for (int s = 0; s < 16; ++s) {
      const int p = s & 1;
      if (s < 15) stage(s + 1, 1 - p);
#pragma unroll
      for (int kk = 0; kk < 2; ++kk) {
        short8 af[4], bf[2];
#pragma unroll
        for (int i = 0; i < 4; ++i)
          af[i] = *(const short8*)(lA + p * 8192 + ((wm * 4 + i) * 2 + kk) * 512
                                   + l15 * 32 + ((quad ^ xslot) << 3));
#pragma unroll
        for (int j = 0; j < 2; ++j)
          bf[j] = *(const short8*)(lBb + p * 4096 + ((wn * 2 + j) * 2 + kk) * 512
                                   + l15 * 32 + ((quad ^ xslot) << 3));
#pragma unroll
        for (int i = 0; i < 4; ++i)
#pragma unroll
          for (int j = 0; j < 2; ++j)
            acc[i][j] = __builtin_amdgcn_mfma_f32_16x16x32_bf16(af[i], bf[j], acc[i][j], 0, 0, 0);
      }
      __syncthreads();
    }

#pragma unroll
    for (int i = 0; i < 4; ++i)
#pragma unroll
      for (int j = 0; j < 2; ++j) {
        const int col = n0 + wn * 32 + j * 16 + l15;
        const float bv = b4[col];
#pragma unroll
        for (int r = 0; r < 4; ++r) {
          const int row = m0 + wm * 64 + i * 16 + quad * 4 + r;
          out[(size_t)row * 512 + col] = acc[i][j][r] + bv;
        }
      }
    return;
  }

  // ================= pairwise role =================
  const int q = blockIdx.x - 512;   // 0..335
  const int cls = q / 21;
  int p = q - cls * 21, ti = 0, cnt = 6;
  while (p >= cnt) { p -= cnt; ++ti; --cnt; }   // block-uniform scalar decode
  const int tj = ti + p;

  const int start = offs[cls];
  const int n = offs[cls + 1] - start;
  if (ti * 128 >= n || tj * 128 >= n) return;

  constexpr int LDA = 66;
  u16* Li = uni;                    // 128*66*2 = 16896 B
  u16* Lj = uni + 128 * LDA;        // +16896 B
  float* sqI = (float*)(uni + 2 * 128 * LDA);       // 512 B
  float* sqJ = sqI + 128;                            // 512 B
  float* red4 = sqJ + 128;                           // 16 B

  for (int e = tid; e < 2048; e += 256) {
    const int t = e >> 10;
    const int row = (e >> 3) & 127;
    const int ch = e & 7;
    const int g = (t ? tj : ti) * 128 + row;
    short8 v = (short8)0;
    if (g < n) {
      v = *(const short8*)(Ebf + (size_t)idx[start + g] * EMBN + ch * 8);
      if (ch == 0) { v[0] = 0; v[1] = 0; }
    }
    *(short8*)((t ? Lj : Li) + row * LDA + ch * 8) = v;
  }
  {
    const int t = tid >> 7, row = tid & 127;
    const int g = (t ? tj : ti) * 128 + row;
    (t ? sqJ : sqI)[row] = (g < n) ? sqrow[idx[start + g]] : 0.f;
  }
  __syncthreads();

  const int wm = wave >> 1, wn = wave & 1;

  floatx4 acc[4][4];
#pragma unroll
  for (int i = 0; i < 4; ++i)
#pragma unroll
    for (int j = 0; j < 4; ++j) acc[i][j] = (floatx4){0.f, 0.f, 0.f, 0.f};

#pragma unroll
  for (int ks = 0; ks < 2; ++ks) {
    short8 af[4], bf[4];
#pragma unroll
    for (int i = 0; i < 4; ++i)
      af[i] = *(const short8*)(Li + (wm * 64 + i * 16 + l15) * LDA + ks * 32 + quad * 8);
#pragma unroll
    for (int j = 0; j < 4; ++j)
      bf[j] = *(const short8*)(Lj + (wn * 64 + j * 16 + l15) * LDA + ks * 32 + quad * 8);
#pragma unroll
    for (int i = 0; i < 4; ++i)
#pragma unroll
      for (int j = 0; j < 4; ++j)
        acc[i][j] = __builtin_amdgcn_mfma_f32_16x16x32_bf16(af[i], bf[j], acc[i][j], 0, 0, 0);
  }

  float local = 0.f;
#pragma unroll
  for (int i = 0; i < 4; ++i)
#pragma unroll
    for (int j = 0; j < 4; ++j)
#pragma unroll
      for (int r = 0; r < 4; ++r) {
        const int row = wm * 64 + i * 16 + quad * 4 + r;
        const int col = wn * 64 + j * 16 + l15;
        const int gi = ti * 128 + row, gj = tj * 128 + col;
        if (gi < n && gj < n && gi != gj) {
          const float D = (sqI[row] + sqJ[col] - 2.f * acc[i][j][r]) * (1.f / 62.f);
          local += fmaxf(0.f, MARGINF - D);
        }
      }
  if (ti < tj) local *= 2.f;

  for (int o = 32; o > 0; o >>= 1) local += __shfl_xor(local, o);
  if (lane == 0) red4[wave] = local;
  __syncthreads();
  if (tid == 0)
    atomicAdd(pair_sum, red4[0] + red4[1] + red4[2] + red4[3]);
}

__device__ __forceinline__ double block_reduce_d(double v, double* red, int tid) {
  red[tid] = v;
  __syncthreads();
  for (int st = 128; st > 0; st >>= 1) {
    if (tid < st) red[tid] += red[tid + st];
    __syncthreads();
  }
  const double r = red[0];
  __syncthreads();
  return r;
}

// C_sim (factored, no N^2) and C_diff from pair_sum + analytic diagonal.
__global__ __launch_bounds__(256)
void finalize(const float* __restrict__ vsumR, const float* __restrict__ SsumR,
              const int* __restrict__ counts, const float* __restrict__ pair_sum,
              float* __restrict__ out2)
{
  const int tid = threadIdx.x;
  __shared__ double red[256];
  __shared__ float vtot[NCLS * NCONS];   // 992 floats

  for (int i = tid; i < NCLS * NCONS; i += 256) {
    float s = 0.f;
    for (int r = 0; r < NREP; ++r) s += vsumR[r * (NCLS * NCONS) + i];
    vtot[i] = s;
  }
  __syncthreads();

  double v = 0.0;
  if (tid < NCLS) {
    float Sc = 0.f;
    for (int r = 0; r < NREP; ++r) Sc += SsumR[r * NCLS + tid];
    v = (double)Sc * (double)(NROWS - counts[tid]);
  }
  const double t1 = block_reduce_d(v, red, tid);            // sum_c S_c (N - n_c)

  v = 0.0;
  if (tid < NCLS) { const double nc = (double)counts[tid]; v = nc * nc; }
  const double n_same = block_reduce_d(v, red, tid);        // sum n_c^2

  v = 0.0;
  for (int i = tid; i < NCLS * NCONS; i += 256) { const double w = vtot[i]; v += w * w; }
  const double t2 = block_reduce_d(v, red, tid);            // sum_c |v_c|^2

  v = 0.0;
  if (tid < NCONS) {
    double Vk = 0.0;
    for (int c = 0; c < NCLS; ++c) Vk += (double)vtot[c * NCONS + tid];
    v = Vk * Vk;
  }
  const double t3 = block_reduce_d(v, red, tid);            // |V|^2

  if (tid == 0) {
    const double n_diff = (double)NROWS * (double)NROWS - n_same;
    const double sim = 2.0 * t1 - 2.0 * (t3 - t2);
    const double C_sim = sim / 62.0 / (n_diff + 1.0);
    const double C_diff = ((double)pair_sum[0] + (double)NROWS * (double)MARGINF)
                          / (n_same + 1.0);
    out2[0] = (float)C_sim;
    out2[1] = (float)C_diff;
  }
}

// ---------------------------------------------------------------------------
// ws_size ~256 MB. Flat ~36 MB. 4 dispatches.
// ---------------------------------------------------------------------------
extern "C" void kernel_launch(void* const* d_in, const int* in_sizes, int n_in,
                              void* d_out, int out_size, void* d_ws, size_t ws_size,
                              hipStream_t stream)
{
  const float* x  = (const float*)d_in[0];
  const float* W1 = (const float*)d_in[1];
  const float* b1 = (const float*)d_in[2];
  const float* W2 = (const float*)d_in[3];
  const float* b2 = (const float*)d_in[4];
  const float* W3 = (const float*)d_in[5];
  const float* b3 = (const float*)d_in[6];
  const float* W4 = (const float*)d_in[7];
  const float* b4 = (const float*)d_in[8];
  float* out = (float*)d_out;

  char* ws = (char*)d_ws;
  const size_t KB = 1024, MB = 1ull << 20;
  u16* A0p    = (u16*)(ws + 0);                    // 8 MB packed A
  u16* W1p    = (u16*)(ws + 8 * MB);               // 1 MB
  u16* W2p    = (u16*)(ws + 9 * MB);               // 128 KB
  u16* W3p    = (u16*)(ws + 9 * MB + 128 * KB);    // 128 KB
  u16* W4p    = (u16*)(ws + 9 * MB + 256 * KB);    // 1 MB
  u16* Ebf    = (u16*)(ws + 18 * MB + 256 * KB);   // 1 MB
  int* labels = (int*)(ws + 19 * MB + 256 * KB);   // 32 KB
  int* idx    = (int*)(ws + 19 * MB + 288 * KB);   // 32 KB
  float* sqrow = (float*)(ws + 19 * MB + 320 * KB);// 32 KB
  int* hist32 = (int*)(ws + 19 * MB + 352 * KB);   // 2 KB (plain stores)
  float* slab = (float*)(ws + 19 * MB + 384 * KB); // 96 KB zeroed in prep_all
  int*   counts  = (int*)slab;                     // [0,16)
  int*   offs    = counts + 16;                    // [16,33)
  float* psum    = slab + 64;                      // 1
  float* SsumR   = slab + 128;                     // 16 x 16
  float* vsumR   = slab + 512;                     // 16 x 992 = 15872
  u16* T      = (u16*)(ws + 20 * MB);              // 16 MB (8192 x 1024 bf16)
  (void)in_sizes; (void)n_in; (void)out_size; (void)ws_size;

  prep_all<<<dim3(2630), dim3(256), 0, stream>>>(x, W1, W2, W3, W4,
                                                 A0p, W1p, W2p, W3p, W4p,
                                                 slab, labels, hist32);
  fused123<<<dim3(528), dim3(512), 0, stream>>>(A0p, W1p, b1, W2p, b2, W3p, b3,
                                                labels, hist32, offs, counts, idx,
                                                Ebf, sqrow, vsumR, SsumR, T);
  tail<<<dim3(848), dim3(256), 0, stream>>>(T, W4p, b4, out,
                                            Ebf, sqrow, idx, offs, psum);
  finalize<<<dim3(1), dim3(256), 0, stream>>>(vsumR, SsumR, counts, psum,
                                              out + (size_t)NROWS * DIN);
}